// Round 1
// baseline (562.594 us; speedup 1.0000x reference)
//
#include <hip/hip_runtime.h>
#include <math.h>

#define TQ 64      // query rows per block
#define BK 64      // K tile
#define NITEM 100
#define CDIM 512
#define HW 4096
#define KTOP 10

// Fused: logits GEMM (fp32 VALU) -> softmax -> top-10 -> renorm softmax -> out tile
__global__ __launch_bounds__(256, 3) void mem_fused(
    const float* __restrict__ x, const float* __restrict__ mp,
    float* __restrict__ out)
{
  // 12288 floats = 48 KB
  __shared__ float smem[12288];
  float* qs  = smem;                 // [BK][64]   q tile, k-major
  float* ms  = smem + 4096;          // [BK][128]  mempool tile, transposed, 8-slot groups of 7 items
  float* ls  = smem;                 // [64][113]  logits (aliases qs/ms after K loop)
  float* wls = smem + 7232;          // [64][KTOP] renormalized weights
  int*   ils = (int*)(smem + 7872);  // [64][KTOP] top-k indices

  const int t    = threadIdx.x;
  const int n0   = blockIdx.x * TQ;
  const int b    = n0 >> 12;           // HW = 4096
  const int nsp0 = n0 & (HW - 1);
  const float* xb = x + (size_t)b * CDIM * HW + nsp0;

  // compute mapping: 16x16 threads, 4 rows x 7 items each
  const int tr = t & 15;
  const int tc = t >> 4;

  float acc[4][7];
  #pragma unroll
  for (int r = 0; r < 4; ++r)
    #pragma unroll
    for (int i = 0; i < 7; ++i) acc[r][i] = 0.f;

  for (int kt = 0; kt < CDIM / BK; ++kt) {
    const int k0 = kt * BK;
    __syncthreads();
    // stage q tile: 64 k-rows x 64 queries, coalesced 256B segments
    #pragma unroll
    for (int m = 0; m < 4; ++m) {
      int j  = t + 256 * m;        // 0..1023 float4 tasks
      int kk = j >> 4, c4 = j & 15;
      float4 v = *(const float4*)(xb + (size_t)(k0 + kk) * HW + c4 * 4);
      *(float4*)(qs + kk * 64 + c4 * 4) = v;
    }
    // stage mempool tile transposed: item-major tasks for conflict-free LDS writes
    #pragma unroll
    for (int m = 0; m < 7; ++m) {
      int j    = t + 256 * m;      // 0..1791 tasks (112 items x 16 c4)
      int c4   = j / 112;
      int item = j - c4 * 112;
      float4 v = make_float4(0.f, 0.f, 0.f, 0.f);
      if (item < NITEM) v = *(const float4*)(mp + item * CDIM + k0 + c4 * 4);
      int col = item + item / 7;   // pack 7 items per 8-slot group (16B-aligned reads)
      ms[(c4 * 4 + 0) * 128 + col] = v.x;
      ms[(c4 * 4 + 1) * 128 + col] = v.y;
      ms[(c4 * 4 + 2) * 128 + col] = v.z;
      ms[(c4 * 4 + 3) * 128 + col] = v.w;
    }
    __syncthreads();
    // fp32 register-tile GEMM: acc[4][7] += q[4] * m[7]
    #pragma unroll 4
    for (int kk = 0; kk < BK; ++kk) {
      float4 qv = *(const float4*)(qs + kk * 64 + tr * 4);
      const float* mr = ms + kk * 128 + tc * 8;
      float4 ma  = *(const float4*)(mr);
      float4 mb2 = *(const float4*)(mr + 4);
      float qq[4] = {qv.x, qv.y, qv.z, qv.w};
      float mv[7] = {ma.x, ma.y, ma.z, ma.w, mb2.x, mb2.y, mb2.z};
      #pragma unroll
      for (int r = 0; r < 4; ++r)
        #pragma unroll
        for (int i = 0; i < 7; ++i)
          acc[r][i] += qq[r] * mv[i];
    }
  }

  __syncthreads();
  // logits -> LDS [64][113] (113 odd => conflict-free row-strided access)
  #pragma unroll
  for (int r = 0; r < 4; ++r)
    #pragma unroll
    for (int i = 0; i < 7; ++i)
      ls[(tr * 4 + r) * 113 + tc * 7 + i] = acc[r][i];
  __syncthreads();

  // per-row softmax + top-10 + renormalized softmax (thread r owns row r)
  if (t < TQ) {
    float* lr = ls + t * 113;
    float mx = -INFINITY;
    #pragma unroll 4
    for (int j = 0; j < NITEM; ++j) mx = fmaxf(mx, lr[j]);
    float Z = 0.f;
    #pragma unroll 4
    for (int j = 0; j < NITEM; ++j) Z += expf(lr[j] - mx);
    float att[KTOP]; int idx[KTOP];
    #pragma unroll 1
    for (int s = 0; s < KTOP; ++s) {
      float vm = -INFINITY; int im = 0;
      #pragma unroll 4
      for (int j = 0; j < NITEM; ++j) {
        float v = lr[j];
        if (v > vm) { vm = v; im = j; }   // strict > : lowest index wins ties (matches top_k)
      }
      lr[im] = -INFINITY;                  // destructive mask
      att[s] = expf(vm - mx) / Z;          // att value (softmax prob)
      idx[s] = im;
    }
    // second softmax over the 10 att values (att[0] is the max)
    float s2 = 0.f; float w[KTOP];
    #pragma unroll
    for (int s = 0; s < KTOP; ++s) { w[s] = expf(att[s] - att[0]); s2 += w[s]; }
    float inv = 1.f / s2;
    #pragma unroll
    for (int s = 0; s < KTOP; ++s) {
      wls[t * KTOP + s] = w[s] * inv;
      ils[t * KTOP + s] = idx[s];
    }
  }
  __syncthreads();

  // reconstruct: out[b][c][n] = sum_s w[s] * mempool[idx[s]][c]; coalesced NCHW stores
  const int r  = t & 63;
  const int cg = t >> 6;
  float wreg[KTOP]; int id[KTOP];
  #pragma unroll
  for (int s = 0; s < KTOP; ++s) {
    wreg[s] = wls[r * KTOP + s];
    id[s]   = ils[r * KTOP + s] * CDIM;
  }
  float* ob = out + (size_t)b * CDIM * HW + nsp0 + r;
  for (int i = 0; i < 32; ++i) {
    int c = cg * 128 + i * 4;
    float a0 = 0.f, a1 = 0.f, a2 = 0.f, a3 = 0.f;
    #pragma unroll
    for (int s = 0; s < KTOP; ++s) {
      float4 mv = *(const float4*)(mp + id[s] + c);
      a0 += wreg[s] * mv.x; a1 += wreg[s] * mv.y;
      a2 += wreg[s] * mv.z; a3 += wreg[s] * mv.w;
    }
    ob[(size_t)(c + 0) * HW] = a0;
    ob[(size_t)(c + 1) * HW] = a1;
    ob[(size_t)(c + 2) * HW] = a2;
    ob[(size_t)(c + 3) * HW] = a3;
  }
}

// loss = sum_{i!=j} |0.5 * dot(m_i, m_j)| / (NITEM*NITEM)
__global__ void loss_partial(const float* __restrict__ mp, float* __restrict__ part)
{
  __shared__ float mi[CDIM];
  __shared__ float red[4];
  const int i = blockIdx.x;
  const int t = threadIdx.x;   // 256
  for (int k = t; k < CDIM; k += 256) mi[k] = mp[i * CDIM + k];
  __syncthreads();
  float v = 0.f;
  if (t < NITEM && t != i) {
    const float* mj = mp + t * CDIM;
    float d = 0.f;
    #pragma unroll 8
    for (int k = 0; k < CDIM; ++k) d += mi[k] * mj[k];
    v = fabsf(0.5f * d);
  }
  #pragma unroll
  for (int o = 32; o > 0; o >>= 1) v += __shfl_down(v, o, 64);
  if ((t & 63) == 0) red[t >> 6] = v;
  __syncthreads();
  if (t == 0) part[i] = red[0] + red[1] + red[2] + red[3];
}

__global__ void loss_final(const float* __restrict__ part, float* __restrict__ out_loss)
{
  if (threadIdx.x == 0) {
    float s = 0.f;
    for (int i = 0; i < NITEM; ++i) s += part[i];
    *out_loss = s / (float)(NITEM * NITEM);
  }
}

extern "C" void kernel_launch(void* const* d_in, const int* in_sizes, int n_in,
                              void* d_out, int out_size, void* d_ws, size_t ws_size,
                              hipStream_t stream) {
  const float* x  = (const float*)d_in[0];
  const float* mp = (const float*)d_in[1];
  float* out  = (float*)d_out;
  float* part = (float*)d_ws;

  const int nblocks = (32 * HW) / TQ;  // 131072 rows / 64 = 2048
  mem_fused<<<nblocks, 256, 0, stream>>>(x, mp, out);
  loss_partial<<<NITEM, 256, 0, stream>>>(mp, part);
  loss_final<<<1, 64, 0, stream>>>(part, out + (out_size - 1));
}

// Round 2
// 427.282 us; speedup vs baseline: 1.3167x; 1.3167x over previous
//
#include <hip/hip_runtime.h>
#include <math.h>

#define NITEM 100
#define CDIM 512
#define HW 4096
#define KTOP 10

typedef __attribute__((ext_vector_type(8))) short bf16x8;
typedef __attribute__((ext_vector_type(4))) float f32x4;

__device__ inline unsigned short bf16u(float f) {
  unsigned int u = __float_as_uint(f);
  u += 0x7fffu + ((u >> 16) & 1u);     // RNE
  return (unsigned short)(u >> 16);
}

// ---- K1: fp32 logits GEMM + softmax + top-10 + renorm -> dense bf16 W [N][112] ----
// 128 threads, 128 query rows per block. BK=32 over CDIM=512.
// Thread map: tc = t&7 (16 items), tr = t>>3 (rows 4tr..4tr+3 and 64+4tr..+3).
__global__ __launch_bounds__(128, 2) void logits_topk(
    const float* __restrict__ x, const float* __restrict__ mp,
    unsigned short* __restrict__ Wd)
{
  __shared__ float smem[12928];            // 51.7 KB
  float* qs = smem;                         // [32][128] q tile (k-major)
  float* ms = smem + 4096;                  // [32][128] mp tile, granule-swizzled
  float* ls = smem;                         // [128][101] logits (aliases after GEMM)

  const int t   = threadIdx.x;
  const int tc  = t & 7;
  const int tr  = t >> 3;
  const int n0  = blockIdx.x * 128;
  const int b   = n0 >> 12;
  const int sp0 = n0 & (HW - 1);
  const float* xb = x + (size_t)b * CDIM * HW + sp0;

  // ms staging: thread t <-> item-slot t. Storage granule swizzle:
  // item-granule h stored at G = ((h&3)<<3)|(h>>2)  (reads hit all 8 bank groups)
  const int h    = t >> 2;
  const int G    = ((h & 3) << 3) | (h >> 2);
  const int mcol = (G << 2) | (t & 3);
  const float* mrow = mp + (size_t)(t < NITEM ? t : 0) * CDIM;

  float acc[8][16];
  #pragma unroll
  for (int j = 0; j < 8; ++j)
    #pragma unroll
    for (int i = 0; i < 16; ++i) acc[j][i] = 0.f;

  const int wv = t >> 6, ln = t & 63;

  for (int kt = 0; kt < 16; ++kt) {
    const int k0 = kt * 32;
    __syncthreads();
    // stage qs: linear [kk][q], coalesced 512B per kk-row
    #pragma unroll
    for (int i = 0; i < 8; ++i) {
      int e  = i * 512 + wv * 256 + ln * 4;
      int kk = e >> 7, q = e & 127;
      float4 v = *(const float4*)(xb + (size_t)(k0 + kk) * HW + q);
      *(float4*)(qs + e) = v;
    }
    // stage ms: item-slot t's 32 k-values, transposed + swizzled
    #pragma unroll
    for (int g = 0; g < 8; ++g) {
      float4 v = make_float4(0.f, 0.f, 0.f, 0.f);
      if (t < NITEM) v = *(const float4*)(mrow + k0 + 4 * g);
      ms[(4*g + 0) * 128 + mcol] = v.x;
      ms[(4*g + 1) * 128 + mcol] = v.y;
      ms[(4*g + 2) * 128 + mcol] = v.z;
      ms[(4*g + 3) * 128 + mcol] = v.w;
    }
    __syncthreads();
    // fp32 register-tile GEMM: acc[8][16] += q[8] * m[16]
    #pragma unroll 2
    for (int kk = 0; kk < 32; ++kk) {
      const float* qr = qs + kk * 128;
      const float* mr = ms + kk * 128;
      float4 qA = *(const float4*)(qr + 4 * tr);        // rows 4tr..+3   (granule tr)
      float4 qB = *(const float4*)(qr + 64 + 4 * tr);   // rows 64+4tr..  (granule tr+16)
      float4 m0 = *(const float4*)(mr + ((0*8 + tc) << 2));  // items 16tc+0..3
      float4 m1 = *(const float4*)(mr + ((1*8 + tc) << 2));  // items 16tc+4..7
      float4 m2 = *(const float4*)(mr + ((2*8 + tc) << 2));  // items 16tc+8..11
      float4 m3 = *(const float4*)(mr + ((3*8 + tc) << 2));  // items 16tc+12..15
      float qv[8]  = {qA.x,qA.y,qA.z,qA.w,qB.x,qB.y,qB.z,qB.w};
      float mv[16] = {m0.x,m0.y,m0.z,m0.w, m1.x,m1.y,m1.z,m1.w,
                      m2.x,m2.y,m2.z,m2.w, m3.x,m3.y,m3.z,m3.w};
      #pragma unroll
      for (int j = 0; j < 8; ++j)
        #pragma unroll
        for (int i = 0; i < 16; ++i)
          acc[j][i] = __builtin_fmaf(qv[j], mv[i], acc[j][i]);
    }
  }

  // ---- epilogue: acc -> ls [128][101] ----
  __syncthreads();
  #pragma unroll
  for (int j = 0; j < 8; ++j) {
    int row = (j < 4) ? (4 * tr + j) : (64 + 4 * tr + (j - 4));
    #pragma unroll
    for (int i = 0; i < 4; ++i)
      #pragma unroll
      for (int jj = 0; jj < 4; ++jj) {
        int it = 16 * tc + 4 * i + jj;
        if (it < 101) ls[row * 101 + it] = acc[j][4 * i + jj];
      }
  }
  __syncthreads();

  // ---- per-row softmax + top-10 + renorm; all 128 threads busy ----
  {
    float* lr = ls + t * 101;
    float mx = -INFINITY;
    #pragma unroll 4
    for (int j = 0; j < NITEM; ++j) mx = fmaxf(mx, lr[j]);
    float Z = 0.f;
    #pragma unroll 4
    for (int j = 0; j < NITEM; ++j) Z += expf(lr[j] - mx);
    float att[KTOP]; int id[KTOP];
    #pragma unroll 1
    for (int s = 0; s < KTOP; ++s) {
      float vm = -INFINITY; int im = 0;
      #pragma unroll 4
      for (int j = 0; j < NITEM; ++j) {
        float v = lr[j];
        if (v > vm) { vm = v; im = j; }   // strict >: lowest index wins ties
      }
      lr[im] = -INFINITY;                 // destructive mask
      att[s] = expf(vm - mx) / Z;
      id[s]  = im;
    }
    // renormalize over top-k (att[0] is the max)
    float s2 = 0.f, w[KTOP];
    #pragma unroll
    for (int s = 0; s < KTOP; ++s) { w[s] = expf(att[s] - att[0]); s2 += w[s]; }
    float inv = 1.f / s2;
    // dense bf16 W row: 112 entries (100 real + 12 zero pad)
    unsigned short* wrow = Wd + (size_t)(n0 + t) * 112;
    float4 z4 = make_float4(0.f, 0.f, 0.f, 0.f);
    #pragma unroll
    for (int f = 0; f < 14; ++f) *(float4*)(wrow + 8 * f) = z4;
    #pragma unroll
    for (int s = 0; s < KTOP; ++s) wrow[id[s]] = bf16u(w[s] * inv);
  }
}

// ---- K2: out^T = mp^T(bf16) x W^T(bf16) via MFMA; tiles 128c x 128n, K=128 ----
__global__ __launch_bounds__(256, 2) void recon(
    const float* __restrict__ mp, const unsigned short* __restrict__ Wd,
    float* __restrict__ out)
{
  __shared__ unsigned short Ash[128 * 136];  // mp^T bf16 [c][k], k-stride 136
  __shared__ unsigned short Bsh[128 * 136];  // W bf16 [n][k]
  const int t  = threadIdx.x;
  const int ct = blockIdx.x & 3, nt = blockIdx.x >> 2;
  const int c0 = ct * 128, n0 = nt * 128;
  const int b  = n0 >> 12, sp0 = n0 & (HW - 1);

  // stage A: (k 0..99) x (c4 0..31) float4 tasks
  #pragma unroll
  for (int j = 0; j < 13; ++j) {
    int task = t + 256 * j;
    if (task < 3200) {
      int k = task >> 5, c4 = (task & 31) << 2;
      float4 v = *(const float4*)(mp + (size_t)k * CDIM + c0 + c4);
      Ash[(c4 + 0) * 136 + k] = bf16u(v.x);
      Ash[(c4 + 1) * 136 + k] = bf16u(v.y);
      Ash[(c4 + 2) * 136 + k] = bf16u(v.z);
      Ash[(c4 + 3) * 136 + k] = bf16u(v.w);
    }
  }
  // A zero-fill k=100..135
  {
    int c = t >> 1, hf = t & 1;
    unsigned int* A32 = (unsigned int*)Ash;
    #pragma unroll
    for (int j = 0; j < 9; ++j) { int k = 100 + 2 * (hf * 9 + j); A32[(c * 136 + k) >> 1] = 0u; }
  }
  // stage B rows (natural [n][112] bf16) + zero-fill k=112..135
  {
    int n = t >> 1, hf = t & 1;
    #pragma unroll
    for (int j = 0; j < 7; ++j) {
      int f = hf * 7 + j;
      *(bf16x8*)(Bsh + n * 136 + 8 * f) = *(const bf16x8*)(Wd + (size_t)(n0 + n) * 112 + 8 * f);
    }
    unsigned int* B32 = (unsigned int*)Bsh;
    #pragma unroll
    for (int j = 0; j < 6; ++j) { int k = 112 + 2 * (hf * 6 + j); B32[(n * 136 + k) >> 1] = 0u; }
  }
  __syncthreads();

  const int w = t >> 6, l = t & 63;
  const int arow = l & 15, kg = l >> 4;    // A/B frag: row/col = l&15, k-group = l>>4
  f32x4 acc[2][8];
  #pragma unroll
  for (int cr = 0; cr < 2; ++cr)
    #pragma unroll
    for (int n = 0; n < 8; ++n) acc[cr][n] = (f32x4){0.f, 0.f, 0.f, 0.f};

  #pragma unroll
  for (int ks = 0; ks < 4; ++ks) {
    bf16x8 a0 = *(bf16x8*)(Ash + ((2*w + 0) * 16 + arow) * 136 + ks * 32 + kg * 8);
    bf16x8 a1 = *(bf16x8*)(Ash + ((2*w + 1) * 16 + arow) * 136 + ks * 32 + kg * 8);
    #pragma unroll
    for (int nn = 0; nn < 8; ++nn) {
      bf16x8 bb = *(bf16x8*)(Bsh + (nn * 16 + arow) * 136 + ks * 32 + kg * 8);
      acc[0][nn] = __builtin_amdgcn_mfma_f32_16x16x32_bf16(a0, bb, acc[0][nn], 0, 0, 0);
      acc[1][nn] = __builtin_amdgcn_mfma_f32_16x16x32_bf16(a1, bb, acc[1][nn], 0, 0, 0);
    }
  }

  // store: D col (l&15) = n (contiguous), row = kg*4 + j = c
  float* ob = out + (size_t)b * CDIM * HW + sp0;
  #pragma unroll
  for (int cr = 0; cr < 2; ++cr) {
    #pragma unroll
    for (int nn = 0; nn < 8; ++nn) {
      int ncol = nn * 16 + arow;
      #pragma unroll
      for (int j = 0; j < 4; ++j) {
        int cc = c0 + (2*w + cr) * 16 + kg * 4 + j;
        ob[(size_t)cc * HW + ncol] = acc[cr][nn][j];
      }
    }
  }
}

// ---- loss: mean |0.5 * off-diag gram| ----
__global__ void loss_partial(const float* __restrict__ mp, float* __restrict__ part)
{
  __shared__ float mi[CDIM];
  __shared__ float red[4];
  const int i = blockIdx.x;
  const int t = threadIdx.x;
  for (int k = t; k < CDIM; k += 256) mi[k] = mp[i * CDIM + k];
  __syncthreads();
  float v = 0.f;
  if (t < NITEM && t != i) {
    const float* mj = mp + t * CDIM;
    float d = 0.f;
    #pragma unroll 8
    for (int k = 0; k < CDIM; ++k) d += mi[k] * mj[k];
    v = fabsf(0.5f * d);
  }
  #pragma unroll
  for (int o = 32; o > 0; o >>= 1) v += __shfl_down(v, o, 64);
  if ((t & 63) == 0) red[t >> 6] = v;
  __syncthreads();
  if (t == 0) part[i] = red[0] + red[1] + red[2] + red[3];
}

__global__ void loss_final(const float* __restrict__ part, float* __restrict__ out_loss)
{
  if (threadIdx.x == 0) {
    float s = 0.f;
    for (int i = 0; i < NITEM; ++i) s += part[i];
    *out_loss = s / (float)(NITEM * NITEM);
  }
}

extern "C" void kernel_launch(void* const* d_in, const int* in_sizes, int n_in,
                              void* d_out, int out_size, void* d_ws, size_t ws_size,
                              hipStream_t stream) {
  const float* x  = (const float*)d_in[0];
  const float* mp = (const float*)d_in[1];
  float* out = (float*)d_out;
  unsigned short* Wd = (unsigned short*)d_ws;                    // 131072*112*2 = 29.36 MB
  float* part = (float*)((char*)d_ws + (size_t)131072 * 112 * 2);

  logits_topk<<<1024, 128, 0, stream>>>(x, mp, Wd);
  recon<<<4096, 256, 0, stream>>>(mp, Wd, out);
  loss_partial<<<NITEM, 256, 0, stream>>>(mp, part);
  loss_final<<<1, 64, 0, stream>>>(part, out + (out_size - 1));
}